// Round 6
// baseline (52.549 us; speedup 1.0000x reference)
//
#include <hip/hip_runtime.h>
#include <math.h>

#define Tn 2048
#define Cn 1024
#define Hn 64

using u16 = unsigned short;
typedef float f32x4 __attribute__((ext_vector_type(4)));
typedef __bf16 bf16x8 __attribute__((ext_vector_type(8)));
typedef u16 u16x8 __attribute__((ext_vector_type(8)));
typedef u16 u16x4 __attribute__((ext_vector_type(4)));

__device__ __forceinline__ u16 f2bf(float f) {
    return __builtin_bit_cast(u16, static_cast<__bf16>(f));
}

// XOR-swizzled u16 index within a [64][64]-u16 LDS tile (octet-level swizzle):
// byte ^= (row&7)<<4  ->  u16col ^= (row&7)<<3.  16B alignment preserved.
#define SWI(r, c) ((r) * 64 + ((c) ^ (((r) & 7) << 3)))

#define LDS3(p) ((__attribute__((address_space(3))) void*)(p))
#define GLB1(p) ((const __attribute__((address_space(1))) void*)(p))

// ---------------------------------------------------------------------------
// W pack: [Wk|Wq|Wv] f32 -> bf16 in MFMA B-fragment order (unchanged).
// ---------------------------------------------------------------------------
__global__ __launch_bounds__(256) void wpack_kernel(
    const float* __restrict__ Wk, const float* __restrict__ Wq,
    const float* __restrict__ Wv, u16* __restrict__ wp)
{
    int slot = blockIdx.x * 256 + threadIdx.x;   // 0..24575
    int n16  = slot >> 11;
    int rem  = slot & 2047;
    int kc   = rem >> 6;
    int lane = rem & 63;
    int l15 = lane & 15, lg = lane >> 4;
    int col = n16 * 16 + l15;                    // 0..191
    const float* __restrict__ Wm = (col < 64) ? Wk : (col < 128) ? Wq : Wv;
    float sc = (col >= 64 && col < 128) ? 0.03125f : 1.0f;
    const float* src = &Wm[(size_t)(col & 63) * Cn + kc * 32 + lg * 8];
    float4 lo = *reinterpret_cast<const float4*>(src);
    float4 hi = *reinterpret_cast<const float4*>(src + 4);
    u16x8 o;
    o[0] = f2bf(lo.x * sc); o[1] = f2bf(lo.y * sc);
    o[2] = f2bf(lo.z * sc); o[3] = f2bf(lo.w * sc);
    o[4] = f2bf(hi.x * sc); o[5] = f2bf(hi.y * sc);
    o[6] = f2bf(hi.z * sc); o[7] = f2bf(hi.w * sc);
    *reinterpret_cast<u16x8*>(&wp[(size_t)slot * 8]) = o;
}

// ---------------------------------------------------------------------------
// QKV projection, single pass (unchanged from R5).
// ---------------------------------------------------------------------------
__global__ __launch_bounds__(512) void qkv_proj(
    const float* __restrict__ x, const u16* __restrict__ wp,
    u16* __restrict__ kb, u16* __restrict__ qb, u16* __restrict__ vb)
{
    __shared__ float xs[2][32 * 68];

    const int tid  = threadIdx.x;
    const int lane = tid & 63;
    const int w    = tid >> 6;        // 0..7
    const int rg   = w & 1;           // rowgroup of 16
    const int cg   = w >> 1;          // colgroup of 48 (3 tiles)
    const int l15  = lane & 15;
    const int lg   = lane >> 4;

    const int row0 = blockIdx.x * 32;
    const int sr   = tid >> 4;
    const int scc  = (tid & 15) << 2;

    f32x4 acc[3];
#pragma unroll
    for (int nt = 0; nt < 3; ++nt)
#pragma unroll
        for (int r = 0; r < 4; ++r) acc[nt][r] = 0.f;

    const float* __restrict__ xsrc = &x[(size_t)(row0 + sr) * Cn + scc];

    float4 g = *reinterpret_cast<const float4*>(xsrc);
    *reinterpret_cast<float4*>(&xs[0][sr * 68 + scc]) = g;
    __syncthreads();

    for (int ks = 0; ks < 16; ++ks) {
        const int cur = ks & 1;
        if (ks < 15)
            g = *reinterpret_cast<const float4*>(xsrc + (ks + 1) * 64);
#pragma unroll
        for (int kc2 = 0; kc2 < 2; ++kc2) {
            const float* ap = &xs[cur][(rg * 16 + l15) * 68 + kc2 * 32 + (lg << 3)];
            f32x4 a0 = *reinterpret_cast<const f32x4*>(ap);
            f32x4 a1 = *reinterpret_cast<const f32x4*>(ap + 4);
            bf16x8 a;
            a[0] = (__bf16)a0[0]; a[1] = (__bf16)a0[1];
            a[2] = (__bf16)a0[2]; a[3] = (__bf16)a0[3];
            a[4] = (__bf16)a1[0]; a[5] = (__bf16)a1[1];
            a[6] = (__bf16)a1[2]; a[7] = (__bf16)a1[3];
            const int kcg = ks * 2 + kc2;
#pragma unroll
            for (int nt = 0; nt < 3; ++nt) {
                const int n16 = cg * 3 + nt;
                bf16x8 bfr = *reinterpret_cast<const bf16x8*>(
                    &wp[(size_t)((n16 * 32 + kcg) * 64 + lane) * 8]);
                acc[nt] = __builtin_amdgcn_mfma_f32_16x16x32_bf16(a, bfr, acc[nt], 0, 0, 0);
            }
        }
        if (ks < 15)
            *reinterpret_cast<float4*>(&xs[cur ^ 1][sr * 68 + scc]) = g;
        __syncthreads();
    }

#pragma unroll
    for (int nt = 0; nt < 3; ++nt) {
        const int n16  = cg * 3 + nt;
        const int col0 = n16 * 16;
        const int mat  = col0 >> 6;
        u16* __restrict__ ob = (mat == 0) ? kb : (mat == 1) ? qb : vb;
        const int h = (col0 & 63) + l15;
#pragma unroll
        for (int reg = 0; reg < 4; ++reg) {
            const int grow = row0 + rg * 16 + (lg << 2) + reg;
            ob[(size_t)grow * Hn + h] = f2bf(acc[nt][reg]);
        }
    }
}

// ---------------------------------------------------------------------------
// Causal flash attention, split-KV, one-shot chunk staging.
// Work unit = (b, 32-row qtile, 256-key chunk); 1152 blocks, 4 waves.
// Wave w stages K-tile w (global_load_lds, pre-swizzled source) + V-tile w
// (reg->transposed scatter, swizzled).  ONE barrier, then both parity steps
// run barrier-free.  Defer-max (THR=8) skips O-rescale; setprio around MFMA.
// LDS: Ks 32KB + VTs 32KB + Pl 9KB = 74.7KB -> 2 blocks/CU.
// ---------------------------------------------------------------------------
__global__ __launch_bounds__(256) void attn(
    const u16* __restrict__ qb, const u16* __restrict__ kb,
    const u16* __restrict__ vb, float* __restrict__ Opart,
    float* __restrict__ mlb)
{
    __shared__ u16 Ks[4][64 * 64];
    __shared__ u16 VTs[4][64 * 64];
    __shared__ u16 Pl[4][16 * 72];

    const int tid  = threadIdx.x;
    const int lane = tid & 63;
    const int w    = tid >> 6;
    const int g    = w >> 1;       // rowgroup 0/1
    const int p    = w & 1;        // key parity
    const int l15  = lane & 15;
    const int lg   = lane >> 4;

    const int bid = blockIdx.x;
    const int b = bid / 288;
    const int r = bid % 288;
    int gq = (int)((sqrtf((float)r + 1.0f) - 1.0f) * 0.5f);
    while (4 * (gq + 1) * (gq + 2) <= r) ++gq;
    while (4 * gq * (gq + 1) > r) --gq;
    const int rr = r - 4 * gq * (gq + 1);
    const int qt = gq * 8 + rr / (gq + 1);
    const int c  = rr % (gq + 1);
    const int c4 = c * 4;

    const int t0  = qt * 32;
    const int wr0 = t0 + g * 16;
    const int nkt = ((t0 + 31) >> 6) + 1;
    int ntt = nkt - c4; if (ntt > 4) ntt = 4;
    const size_t kvbase = (size_t)b * Tn * Hn;

    // Q fragments
    bf16x8 qf[2];
    {
        const u16* qrow = qb + ((size_t)(b * Tn + wr0 + l15)) * Hn;
        qf[0] = *reinterpret_cast<const bf16x8*>(&qrow[(lg << 3)]);
        qf[1] = *reinterpret_cast<const bf16x8*>(&qrow[32 + (lg << 3)]);
    }

    // ---- stage: wave w handles tile w ----
    if (w < ntt) {
        const int kt = c4 + w;
        const u16* __restrict__ ksrc = kb + kvbase + (size_t)kt * 64 * Hn;
        const u16* __restrict__ vsrc = vb + kvbase + (size_t)(kt * 64 + lane) * Hn;
        // K: global_load_lds, source pre-swizzled so linear dest = swizzled layout
#pragma unroll
        for (int i = 0; i < 8; ++i) {
            const int rw = i * 8 + (lane >> 3);
            const int co = (((lane & 7) ^ (rw & 7)) << 3);
            __builtin_amdgcn_global_load_lds(
                GLB1(ksrc + rw * Hn + co), LDS3(&Ks[w][i * 512]), 16, 0, 0);
        }
        // V: reg-staged, transposed scatter (swizzled)
        u16x8 vr[8];
#pragma unroll
        for (int i = 0; i < 8; ++i)
            vr[i] = *reinterpret_cast<const u16x8*>(&vsrc[i * 8]);
#pragma unroll
        for (int i = 0; i < 8; ++i)
#pragma unroll
            for (int j = 0; j < 8; ++j)
                VTs[w][SWI(i * 8 + j, lane)] = vr[i][j];
    }
    __syncthreads();

    f32x4 o[4];
    float m[4], ls[4];
#pragma unroll
    for (int nt = 0; nt < 4; ++nt)
#pragma unroll
        for (int rg2 = 0; rg2 < 4; ++rg2) o[nt][rg2] = 0.f;
#pragma unroll
    for (int rg2 = 0; rg2 < 4; ++rg2) { m[rg2] = -INFINITY; ls[rg2] = 0.f; }

#pragma unroll
    for (int s = 0; s < 2; ++s) {
        const int tt = 2 * s + p;
        const int mykt = c4 + tt;
        if (mykt < nkt) {
            // QK^T
            f32x4 sf[4];
#pragma unroll
            for (int nt = 0; nt < 4; ++nt)
#pragma unroll
                for (int rg2 = 0; rg2 < 4; ++rg2) sf[nt][rg2] = 0.f;
            __builtin_amdgcn_s_setprio(1);
#pragma unroll
            for (int kc = 0; kc < 2; ++kc) {
#pragma unroll
                for (int nt = 0; nt < 4; ++nt) {
                    bf16x8 kf = *reinterpret_cast<const bf16x8*>(
                        &Ks[tt][SWI(nt * 16 + l15, kc * 32 + (lg << 3))]);
                    sf[nt] = __builtin_amdgcn_mfma_f32_16x16x32_bf16(qf[kc], kf, sf[nt], 0, 0, 0);
                }
            }
            __builtin_amdgcn_s_setprio(0);
            // causal mask (diagonal tiles only)
            if (mykt * 64 + 63 > wr0) {
#pragma unroll
                for (int nt = 0; nt < 4; ++nt) {
                    int kg = mykt * 64 + nt * 16 + l15;
#pragma unroll
                    for (int reg = 0; reg < 4; ++reg) {
                        int tq = wr0 + (lg << 2) + reg;
                        if (kg > tq) sf[nt][reg] = -INFINITY;
                    }
                }
            }
            // tile max + defer-max test
            float tm[4];
            bool defok = true;
#pragma unroll
            for (int reg = 0; reg < 4; ++reg) {
                float t = fmaxf(fmaxf(sf[0][reg], sf[1][reg]),
                                fmaxf(sf[2][reg], sf[3][reg]));
#pragma unroll
                for (int off = 1; off < 16; off <<= 1)
                    t = fmaxf(t, __shfl_xor(t, off, 64));
                tm[reg] = t;
                defok = defok && (t <= m[reg] + 8.f);
            }
            if (!__all(defok ? 1 : 0)) {
#pragma unroll
                for (int reg = 0; reg < 4; ++reg) {
                    float nm = fmaxf(m[reg], tm[reg]);
                    float al = __expf(m[reg] - nm);
                    ls[reg] *= al;
#pragma unroll
                    for (int nt = 0; nt < 4; ++nt) o[nt][reg] *= al;
                    m[reg] = nm;
                }
            }
            // P = exp(S - m), row-sum, store to per-wave LDS
            float pv[4][4];
#pragma unroll
            for (int reg = 0; reg < 4; ++reg) {
                float rs = 0.f;
#pragma unroll
                for (int nt = 0; nt < 4; ++nt) {
                    pv[nt][reg] = __expf(sf[nt][reg] - m[reg]);
                    rs += pv[nt][reg];
                }
#pragma unroll
                for (int off = 1; off < 16; off <<= 1)
                    rs += __shfl_xor(rs, off, 64);
                ls[reg] += rs;
            }
#pragma unroll
            for (int nt = 0; nt < 4; ++nt)
#pragma unroll
                for (int reg = 0; reg < 4; ++reg)
                    Pl[w][((lg << 2) + reg) * 72 + nt * 16 + l15] = f2bf(pv[nt][reg]);
            // PV
#pragma unroll
            for (int kc = 0; kc < 2; ++kc) {
                bf16x8 pa = *reinterpret_cast<const bf16x8*>(
                    &Pl[w][l15 * 72 + kc * 32 + (lg << 3)]);
                __builtin_amdgcn_s_setprio(1);
#pragma unroll
                for (int nt = 0; nt < 4; ++nt) {
                    bf16x8 vf = *reinterpret_cast<const bf16x8*>(
                        &VTs[tt][SWI(nt * 16 + l15, kc * 32 + (lg << 3))]);
                    o[nt] = __builtin_amdgcn_mfma_f32_16x16x32_bf16(pa, vf, o[nt], 0, 0, 0);
                }
                __builtin_amdgcn_s_setprio(0);
            }
        }
    }

    // in-block parity merge -> f32 partial (unnormalized O, m, l)
    __syncthreads();
    float* slab = reinterpret_cast<float*>(&Ks[0][0]);
    float* sb = slab + g * (24 * 64);
    if (p == 1) {
#pragma unroll
        for (int nt = 0; nt < 4; ++nt)
#pragma unroll
            for (int reg = 0; reg < 4; ++reg)
                sb[(nt * 4 + reg) * 64 + lane] = o[nt][reg];
#pragma unroll
        for (int reg = 0; reg < 4; ++reg) {
            sb[(16 + reg) * 64 + lane] = m[reg];
            sb[(20 + reg) * 64 + lane] = ls[reg];
        }
    }
    __syncthreads();
    if (p == 0) {
        const size_t pidx = (size_t)(b * 64 + qt) * 8 + c;
        float* __restrict__ ob = Opart + pidx * 2048;
#pragma unroll
        for (int reg = 0; reg < 4; ++reg) {
            float mB = sb[(16 + reg) * 64 + lane];
            float lB = sb[(20 + reg) * 64 + lane];
            float ms = fmaxf(m[reg], mB);
            float aA = __expf(m[reg] - ms);
            float aB = __expf(mB - ms);
            int row32 = g * 16 + (lg << 2) + reg;
            if (l15 == 0) {
                float* mlp = mlb + pidx * 64 + row32 * 2;
                mlp[0] = ms;
                mlp[1] = aA * ls[reg] + aB * lB;
            }
#pragma unroll
            for (int nt = 0; nt < 4; ++nt)
                ob[row32 * 64 + nt * 16 + l15] =
                    aA * o[nt][reg] + aB * sb[(nt * 4 + reg) * 64 + lane];
        }
    }
}

// ---------------------------------------------------------------------------
// Combine KV-chunk partials (two-phase: independent loads).  grid 256.
// ---------------------------------------------------------------------------
__global__ __launch_bounds__(256) void attn_merge(
    const float* __restrict__ Opart, const float* __restrict__ mlb,
    float* __restrict__ out)
{
    const int bid = blockIdx.x;
    const int b = bid >> 6, qt = bid & 63;
    const int nch = (qt >> 3) + 1;
    const int t = threadIdx.x;
    const int row = t >> 3, d0 = (t & 7) << 3;
    const size_t pbase = (size_t)(b * 64 + qt) * 8;

    float mc[8], lc[8];
#pragma unroll
    for (int cc = 0; cc < 8; ++cc) {
        if (cc < nch) {
            const float* mlp = mlb + (pbase + cc) * 64 + row * 2;
            mc[cc] = mlp[0];
            lc[cc] = mlp[1];
        } else { mc[cc] = -INFINITY; lc[cc] = 0.f; }
    }
    float mfin = mc[0];
#pragma unroll
    for (int cc = 1; cc < 8; ++cc) mfin = fmaxf(mfin, mc[cc]);

    float wgt[8], l = 0.f;
#pragma unroll
    for (int cc = 0; cc < 8; ++cc) {
        wgt[cc] = (cc < nch) ? __expf(mc[cc] - mfin) : 0.f;
        l += lc[cc] * wgt[cc];
    }

    f32x4 O0 = {0.f, 0.f, 0.f, 0.f}, O1 = {0.f, 0.f, 0.f, 0.f};
#pragma unroll
    for (int cc = 0; cc < 8; ++cc) {
        if (cc < nch) {
            const float* op = Opart + (pbase + cc) * 2048 + row * 64 + d0;
            f32x4 c0 = *reinterpret_cast<const f32x4*>(op);
            f32x4 c1 = *reinterpret_cast<const f32x4*>(op + 4);
            O0 += c0 * wgt[cc];
            O1 += c1 * wgt[cc];
        }
    }
    float inv = 1.f / l;
    float* orow = out + ((size_t)(b * Tn + qt * 32 + row)) * Hn + d0;
    *reinterpret_cast<f32x4*>(orow)     = O0 * inv;
    *reinterpret_cast<f32x4*>(orow + 4) = O1 * inv;
}

extern "C" void kernel_launch(void* const* d_in, const int* in_sizes, int n_in,
                              void* d_out, int out_size, void* d_ws, size_t ws_size,
                              hipStream_t stream) {
    const float* x  = (const float*)d_in[0];
    const float* Wk = (const float*)d_in[1];
    const float* Wq = (const float*)d_in[2];
    const float* Wv = (const float*)d_in[3];
    float* out = (float*)d_out;

    const size_t rows = (size_t)4 * Tn;            // 8192
    u16* kbuf = (u16*)d_ws;                        // [8192][64] bf16
    u16* qbuf = kbuf + rows * Hn;
    u16* vbuf = qbuf + rows * Hn;
    u16* wpk  = vbuf + rows * Hn;                  // 196608 u16
    float* Opart = (float*)(wpk + 196608);         // [256][8][32][64] f32
    float* mlb   = Opart + (size_t)4 * 64 * 8 * 2048;  // [256][8][32][2] f32

    wpack_kernel<<<96, 256, 0, stream>>>(Wk, Wq, Wv, wpk);
    qkv_proj<<<256, 512, 0, stream>>>(x, wpk, kbuf, qbuf, vbuf);
    attn<<<1152, 256, 0, stream>>>(qbuf, kbuf, vbuf, Opart, mlb);
    attn_merge<<<256, 256, 0, stream>>>(Opart, mlb, out);
}

// Round 7
// 49.218 us; speedup vs baseline: 1.0677x; 1.0677x over previous
//
#include <hip/hip_runtime.h>
#include <math.h>

#define Tn 2048
#define Cn 1024
#define Hn 64

using u16 = unsigned short;
typedef float f32x4 __attribute__((ext_vector_type(4)));
typedef __bf16 bf16x8 __attribute__((ext_vector_type(8)));
typedef u16 u16x8 __attribute__((ext_vector_type(8)));
typedef u16 u16x4 __attribute__((ext_vector_type(4)));

__device__ __forceinline__ u16 f2bf(float f) {
    return __builtin_bit_cast(u16, static_cast<__bf16>(f));
}

// ---------------------------------------------------------------------------
// W pack: [Wk|Wq|Wv] f32 -> bf16 in MFMA B-fragment order (unchanged).
// ---------------------------------------------------------------------------
__global__ __launch_bounds__(256) void wpack_kernel(
    const float* __restrict__ Wk, const float* __restrict__ Wq,
    const float* __restrict__ Wv, u16* __restrict__ wp)
{
    int slot = blockIdx.x * 256 + threadIdx.x;   // 0..24575
    int n16  = slot >> 11;
    int rem  = slot & 2047;
    int kc   = rem >> 6;
    int lane = rem & 63;
    int l15 = lane & 15, lg = lane >> 4;
    int col = n16 * 16 + l15;                    // 0..191
    const float* __restrict__ Wm = (col < 64) ? Wk : (col < 128) ? Wq : Wv;
    float sc = (col >= 64 && col < 128) ? 0.03125f : 1.0f;
    const float* src = &Wm[(size_t)(col & 63) * Cn + kc * 32 + lg * 8];
    float4 lo = *reinterpret_cast<const float4*>(src);
    float4 hi = *reinterpret_cast<const float4*>(src + 4);
    u16x8 o;
    o[0] = f2bf(lo.x * sc); o[1] = f2bf(lo.y * sc);
    o[2] = f2bf(lo.z * sc); o[3] = f2bf(lo.w * sc);
    o[4] = f2bf(hi.x * sc); o[5] = f2bf(hi.y * sc);
    o[6] = f2bf(hi.z * sc); o[7] = f2bf(hi.w * sc);
    *reinterpret_cast<u16x8*>(&wp[(size_t)slot * 8]) = o;
}

// ---------------------------------------------------------------------------
// QKV projection, single pass (unchanged from R5).
// ---------------------------------------------------------------------------
__global__ __launch_bounds__(512) void qkv_proj(
    const float* __restrict__ x, const u16* __restrict__ wp,
    u16* __restrict__ kb, u16* __restrict__ qb, u16* __restrict__ vb)
{
    __shared__ float xs[2][32 * 68];

    const int tid  = threadIdx.x;
    const int lane = tid & 63;
    const int w    = tid >> 6;        // 0..7
    const int rg   = w & 1;           // rowgroup of 16
    const int cg   = w >> 1;          // colgroup of 48 (3 tiles)
    const int l15  = lane & 15;
    const int lg   = lane >> 4;

    const int row0 = blockIdx.x * 32;
    const int sr   = tid >> 4;
    const int scc  = (tid & 15) << 2;

    f32x4 acc[3];
#pragma unroll
    for (int nt = 0; nt < 3; ++nt)
#pragma unroll
        for (int r = 0; r < 4; ++r) acc[nt][r] = 0.f;

    const float* __restrict__ xsrc = &x[(size_t)(row0 + sr) * Cn + scc];

    float4 g = *reinterpret_cast<const float4*>(xsrc);
    *reinterpret_cast<float4*>(&xs[0][sr * 68 + scc]) = g;
    __syncthreads();

    for (int ks = 0; ks < 16; ++ks) {
        const int cur = ks & 1;
        if (ks < 15)
            g = *reinterpret_cast<const float4*>(xsrc + (ks + 1) * 64);
#pragma unroll
        for (int kc2 = 0; kc2 < 2; ++kc2) {
            const float* ap = &xs[cur][(rg * 16 + l15) * 68 + kc2 * 32 + (lg << 3)];
            f32x4 a0 = *reinterpret_cast<const f32x4*>(ap);
            f32x4 a1 = *reinterpret_cast<const f32x4*>(ap + 4);
            bf16x8 a;
            a[0] = (__bf16)a0[0]; a[1] = (__bf16)a0[1];
            a[2] = (__bf16)a0[2]; a[3] = (__bf16)a0[3];
            a[4] = (__bf16)a1[0]; a[5] = (__bf16)a1[1];
            a[6] = (__bf16)a1[2]; a[7] = (__bf16)a1[3];
            const int kcg = ks * 2 + kc2;
#pragma unroll
            for (int nt = 0; nt < 3; ++nt) {
                const int n16 = cg * 3 + nt;
                bf16x8 bfr = *reinterpret_cast<const bf16x8*>(
                    &wp[(size_t)((n16 * 32 + kcg) * 64 + lane) * 8]);
                acc[nt] = __builtin_amdgcn_mfma_f32_16x16x32_bf16(a, bfr, acc[nt], 0, 0, 0);
            }
        }
        if (ks < 15)
            *reinterpret_cast<float4*>(&xs[cur ^ 1][sr * 68 + scc]) = g;
        __syncthreads();
    }

#pragma unroll
    for (int nt = 0; nt < 3; ++nt) {
        const int n16  = cg * 3 + nt;
        const int col0 = n16 * 16;
        const int mat  = col0 >> 6;
        u16* __restrict__ ob = (mat == 0) ? kb : (mat == 1) ? qb : vb;
        const int h = (col0 & 63) + l15;
#pragma unroll
        for (int reg = 0; reg < 4; ++reg) {
            const int grow = row0 + rg * 16 + (lg << 2) + reg;
            ob[(size_t)grow * Hn + h] = f2bf(acc[nt][reg]);
        }
    }
}

// ---------------------------------------------------------------------------
// Causal flash attention, split-KV (R5 structure: padded-72 LDS, per-s-step
// staging, 3 blocks/CU).  Added this round: defer-max (T13, THR=8) and
// setprio around MFMA clusters (T5).  Work unit = (b, 32-row qtile, 256-key
// chunk); 1152 blocks; 4 waves = 2 rowgroups x 2 key-parities.
// ---------------------------------------------------------------------------
__global__ __launch_bounds__(256) void attn(
    const u16* __restrict__ qb, const u16* __restrict__ kb,
    const u16* __restrict__ vb, float* __restrict__ Opart,
    float* __restrict__ mlb)
{
    __shared__ u16 Ks[2][64 * 72];
    __shared__ u16 VTs[2][64 * 72];
    __shared__ u16 Pl[4][16 * 72];

    const int tid  = threadIdx.x;
    const int lane = tid & 63;
    const int w    = tid >> 6;
    const int g    = w >> 1;
    const int p    = w & 1;
    const int l15  = lane & 15;
    const int lg   = lane >> 4;

    const int bid = blockIdx.x;
    const int b = bid / 288;
    const int r = bid % 288;
    int gq = (int)((sqrtf((float)r + 1.0f) - 1.0f) * 0.5f);
    while (4 * (gq + 1) * (gq + 2) <= r) ++gq;
    while (4 * gq * (gq + 1) > r) --gq;
    const int rr = r - 4 * gq * (gq + 1);
    const int qt = gq * 8 + rr / (gq + 1);
    const int c  = rr % (gq + 1);

    const int t0  = qt * 32;
    const int wr0 = t0 + g * 16;
    const int nkt = ((t0 + 31) >> 6) + 1;
    const size_t kvbase = (size_t)b * Tn * Hn;

    bf16x8 qf[2];
    {
        const u16* qrow = qb + ((size_t)(b * Tn + wr0 + l15)) * Hn;
        qf[0] = *reinterpret_cast<const bf16x8*>(&qrow[(lg << 3)]);
        qf[1] = *reinterpret_cast<const bf16x8*>(&qrow[32 + (lg << 3)]);
    }

    f32x4 o[4];
    float m[4], ls[4];
#pragma unroll
    for (int nt = 0; nt < 4; ++nt)
#pragma unroll
        for (int rg2 = 0; rg2 < 4; ++rg2) o[nt][rg2] = 0.f;
#pragma unroll
    for (int rg2 = 0; rg2 < 4; ++rg2) { m[rg2] = -INFINITY; ls[rg2] = 0.f; }

    for (int s = 0; s < 2; ++s) {
        const int kt0 = c * 4 + 2 * s, kt1 = kt0 + 1;
        if (kt0 < nkt) {
#pragma unroll
            for (int i = 0; i < 2; ++i) {
                int cc = tid + 256 * i;
                int rr2 = cc >> 3, c8 = (cc & 7) << 3;
                *reinterpret_cast<u16x8*>(&Ks[0][rr2 * 72 + c8]) =
                    *reinterpret_cast<const u16x8*>(&kb[kvbase + (size_t)(kt0 * 64 + rr2) * Hn + c8]);
            }
#pragma unroll
            for (int i = 0; i < 2; ++i) {
                int cc = tid + 256 * i;
                int k = cc & 63, d0 = (cc >> 6) << 3;
                u16x8 v = *reinterpret_cast<const u16x8*>(&vb[kvbase + (size_t)(kt0 * 64 + k) * Hn + d0]);
#pragma unroll
                for (int j = 0; j < 8; ++j) VTs[0][(d0 + j) * 72 + k] = v[j];
            }
        }
        if (kt1 < nkt) {
#pragma unroll
            for (int i = 0; i < 2; ++i) {
                int cc = tid + 256 * i;
                int rr2 = cc >> 3, c8 = (cc & 7) << 3;
                *reinterpret_cast<u16x8*>(&Ks[1][rr2 * 72 + c8]) =
                    *reinterpret_cast<const u16x8*>(&kb[kvbase + (size_t)(kt1 * 64 + rr2) * Hn + c8]);
            }
#pragma unroll
            for (int i = 0; i < 2; ++i) {
                int cc = tid + 256 * i;
                int k = cc & 63, d0 = (cc >> 6) << 3;
                u16x8 v = *reinterpret_cast<const u16x8*>(&vb[kvbase + (size_t)(kt1 * 64 + k) * Hn + d0]);
#pragma unroll
                for (int j = 0; j < 8; ++j) VTs[1][(d0 + j) * 72 + k] = v[j];
            }
        }
        __syncthreads();

        const int mykt = kt0 + p;
        if (mykt < nkt) {
            f32x4 sf[4];
#pragma unroll
            for (int nt = 0; nt < 4; ++nt)
#pragma unroll
                for (int rg2 = 0; rg2 < 4; ++rg2) sf[nt][rg2] = 0.f;
            __builtin_amdgcn_s_setprio(1);
#pragma unroll
            for (int kc = 0; kc < 2; ++kc) {
#pragma unroll
                for (int nt = 0; nt < 4; ++nt) {
                    bf16x8 kf = *reinterpret_cast<const bf16x8*>(
                        &Ks[p][(nt * 16 + l15) * 72 + kc * 32 + (lg << 3)]);
                    sf[nt] = __builtin_amdgcn_mfma_f32_16x16x32_bf16(qf[kc], kf, sf[nt], 0, 0, 0);
                }
            }
            __builtin_amdgcn_s_setprio(0);
            if (mykt * 64 + 63 > wr0) {
#pragma unroll
                for (int nt = 0; nt < 4; ++nt) {
                    int kg = mykt * 64 + nt * 16 + l15;
#pragma unroll
                    for (int reg = 0; reg < 4; ++reg) {
                        int tq = wr0 + (lg << 2) + reg;
                        if (kg > tq) sf[nt][reg] = -INFINITY;
                    }
                }
            }
            // tile max + defer-max (THR=8): skip O-rescale when max growth small
            float tm[4];
            bool defok = true;
#pragma unroll
            for (int reg = 0; reg < 4; ++reg) {
                float t = fmaxf(fmaxf(sf[0][reg], sf[1][reg]),
                                fmaxf(sf[2][reg], sf[3][reg]));
#pragma unroll
                for (int off = 1; off < 16; off <<= 1)
                    t = fmaxf(t, __shfl_xor(t, off, 64));
                tm[reg] = t;
                defok = defok && (t <= m[reg] + 8.f);
            }
            if (!__all(defok ? 1 : 0)) {
#pragma unroll
                for (int reg = 0; reg < 4; ++reg) {
                    float nm = fmaxf(m[reg], tm[reg]);
                    float al = __expf(m[reg] - nm);   // first tile: m=-inf -> al=0
                    ls[reg] *= al;
#pragma unroll
                    for (int nt = 0; nt < 4; ++nt) o[nt][reg] *= al;
                    m[reg] = nm;
                }
            }
            float pv[4][4];
#pragma unroll
            for (int reg = 0; reg < 4; ++reg) {
                float rs = 0.f;
#pragma unroll
                for (int nt = 0; nt < 4; ++nt) {
                    pv[nt][reg] = __expf(sf[nt][reg] - m[reg]);
                    rs += pv[nt][reg];
                }
#pragma unroll
                for (int off = 1; off < 16; off <<= 1)
                    rs += __shfl_xor(rs, off, 64);
                ls[reg] += rs;
            }
#pragma unroll
            for (int nt = 0; nt < 4; ++nt)
#pragma unroll
                for (int reg = 0; reg < 4; ++reg)
                    Pl[w][((lg << 2) + reg) * 72 + nt * 16 + l15] = f2bf(pv[nt][reg]);
#pragma unroll
            for (int kc = 0; kc < 2; ++kc) {
                bf16x8 pa = *reinterpret_cast<const bf16x8*>(
                    &Pl[w][l15 * 72 + kc * 32 + (lg << 3)]);
                __builtin_amdgcn_s_setprio(1);
#pragma unroll
                for (int nt = 0; nt < 4; ++nt) {
                    bf16x8 vf = *reinterpret_cast<const bf16x8*>(
                        &VTs[p][(nt * 16 + l15) * 72 + kc * 32 + (lg << 3)]);
                    o[nt] = __builtin_amdgcn_mfma_f32_16x16x32_bf16(pa, vf, o[nt], 0, 0, 0);
                }
                __builtin_amdgcn_s_setprio(0);
            }
        }
        __syncthreads();
    }

    // in-block parity merge -> f32 partial (unnormalized O, m, l)
    float* slab = reinterpret_cast<float*>(&Ks[0][0]);
    float* sb = slab + g * (24 * 64);
    if (p == 1) {
#pragma unroll
        for (int nt = 0; nt < 4; ++nt)
#pragma unroll
            for (int reg = 0; reg < 4; ++reg)
                sb[(nt * 4 + reg) * 64 + lane] = o[nt][reg];
#pragma unroll
        for (int reg = 0; reg < 4; ++reg) {
            sb[(16 + reg) * 64 + lane] = m[reg];
            sb[(20 + reg) * 64 + lane] = ls[reg];
        }
    }
    __syncthreads();
    if (p == 0) {
        const size_t pidx = (size_t)(b * 64 + qt) * 8 + c;
        float* __restrict__ ob = Opart + pidx * 2048;
#pragma unroll
        for (int reg = 0; reg < 4; ++reg) {
            float mB = sb[(16 + reg) * 64 + lane];
            float lB = sb[(20 + reg) * 64 + lane];
            float ms = fmaxf(m[reg], mB);
            float aA = __expf(m[reg] - ms);
            float aB = __expf(mB - ms);
            int row32 = g * 16 + (lg << 2) + reg;
            if (l15 == 0) {
                float* mlp = mlb + pidx * 64 + row32 * 2;
                mlp[0] = ms;
                mlp[1] = aA * ls[reg] + aB * lB;
            }
#pragma unroll
            for (int nt = 0; nt < 4; ++nt)
                ob[row32 * 64 + nt * 16 + l15] =
                    aA * o[nt][reg] + aB * sb[(nt * 4 + reg) * 64 + lane];
        }
    }
}

// ---------------------------------------------------------------------------
// Combine KV-chunk partials (two-phase: independent loads).  grid 256.
// ---------------------------------------------------------------------------
__global__ __launch_bounds__(256) void attn_merge(
    const float* __restrict__ Opart, const float* __restrict__ mlb,
    float* __restrict__ out)
{
    const int bid = blockIdx.x;
    const int b = bid >> 6, qt = bid & 63;
    const int nch = (qt >> 3) + 1;
    const int t = threadIdx.x;
    const int row = t >> 3, d0 = (t & 7) << 3;
    const size_t pbase = (size_t)(b * 64 + qt) * 8;

    float mc[8], lc[8];
#pragma unroll
    for (int cc = 0; cc < 8; ++cc) {
        if (cc < nch) {
            const float* mlp = mlb + (pbase + cc) * 64 + row * 2;
            mc[cc] = mlp[0];
            lc[cc] = mlp[1];
        } else { mc[cc] = -INFINITY; lc[cc] = 0.f; }
    }
    float mfin = mc[0];
#pragma unroll
    for (int cc = 1; cc < 8; ++cc) mfin = fmaxf(mfin, mc[cc]);

    float wgt[8], l = 0.f;
#pragma unroll
    for (int cc = 0; cc < 8; ++cc) {
        wgt[cc] = (cc < nch) ? __expf(mc[cc] - mfin) : 0.f;
        l += lc[cc] * wgt[cc];
    }

    f32x4 O0 = {0.f, 0.f, 0.f, 0.f}, O1 = {0.f, 0.f, 0.f, 0.f};
#pragma unroll
    for (int cc = 0; cc < 8; ++cc) {
        if (cc < nch) {
            const float* op = Opart + (pbase + cc) * 2048 + row * 64 + d0;
            f32x4 c0 = *reinterpret_cast<const f32x4*>(op);
            f32x4 c1 = *reinterpret_cast<const f32x4*>(op + 4);
            O0 += c0 * wgt[cc];
            O1 += c1 * wgt[cc];
        }
    }
    float inv = 1.f / l;
    float* orow = out + ((size_t)(b * Tn + qt * 32 + row)) * Hn + d0;
    *reinterpret_cast<f32x4*>(orow)     = O0 * inv;
    *reinterpret_cast<f32x4*>(orow + 4) = O1 * inv;
}

extern "C" void kernel_launch(void* const* d_in, const int* in_sizes, int n_in,
                              void* d_out, int out_size, void* d_ws, size_t ws_size,
                              hipStream_t stream) {
    const float* x  = (const float*)d_in[0];
    const float* Wk = (const float*)d_in[1];
    const float* Wq = (const float*)d_in[2];
    const float* Wv = (const float*)d_in[3];
    float* out = (float*)d_out;

    const size_t rows = (size_t)4 * Tn;            // 8192
    u16* kbuf = (u16*)d_ws;                        // [8192][64] bf16
    u16* qbuf = kbuf + rows * Hn;
    u16* vbuf = qbuf + rows * Hn;
    u16* wpk  = vbuf + rows * Hn;                  // 196608 u16
    float* Opart = (float*)(wpk + 196608);         // [256][8][32][64] f32
    float* mlb   = Opart + (size_t)4 * 64 * 8 * 2048;  // [256][8][32][2] f32

    wpack_kernel<<<96, 256, 0, stream>>>(Wk, Wq, Wv, wpk);
    qkv_proj<<<256, 512, 0, stream>>>(x, wpk, kbuf, qbuf, vbuf);
    attn<<<1152, 256, 0, stream>>>(qbuf, kbuf, vbuf, Opart, mlb);
    attn_merge<<<256, 256, 0, stream>>>(Opart, mlb, out);
}

// Round 8
// 46.603 us; speedup vs baseline: 1.1276x; 1.0561x over previous
//
#include <hip/hip_runtime.h>
#include <math.h>

#define Tn 2048
#define Cn 1024
#define Hn 64

using u16 = unsigned short;
typedef float f32x4 __attribute__((ext_vector_type(4)));
typedef __bf16 bf16x8 __attribute__((ext_vector_type(8)));
typedef u16 u16x8 __attribute__((ext_vector_type(8)));
typedef u16 u16x4 __attribute__((ext_vector_type(4)));

__device__ __forceinline__ u16 f2bf(float f) {
    return __builtin_bit_cast(u16, static_cast<__bf16>(f));
}

// ---------------------------------------------------------------------------
// W pack: [Wk|Wq|Wv] f32 -> bf16 in MFMA B-fragment order (unchanged).
// ---------------------------------------------------------------------------
__global__ __launch_bounds__(256) void wpack_kernel(
    const float* __restrict__ Wk, const float* __restrict__ Wq,
    const float* __restrict__ Wv, u16* __restrict__ wp)
{
    int slot = blockIdx.x * 256 + threadIdx.x;   // 0..24575
    int n16  = slot >> 11;
    int rem  = slot & 2047;
    int kc   = rem >> 6;
    int lane = rem & 63;
    int l15 = lane & 15, lg = lane >> 4;
    int col = n16 * 16 + l15;                    // 0..191
    const float* __restrict__ Wm = (col < 64) ? Wk : (col < 128) ? Wq : Wv;
    float sc = (col >= 64 && col < 128) ? 0.03125f : 1.0f;
    const float* src = &Wm[(size_t)(col & 63) * Cn + kc * 32 + lg * 8];
    float4 lo = *reinterpret_cast<const float4*>(src);
    float4 hi = *reinterpret_cast<const float4*>(src + 4);
    u16x8 o;
    o[0] = f2bf(lo.x * sc); o[1] = f2bf(lo.y * sc);
    o[2] = f2bf(lo.z * sc); o[3] = f2bf(lo.w * sc);
    o[4] = f2bf(hi.x * sc); o[5] = f2bf(hi.y * sc);
    o[6] = f2bf(hi.z * sc); o[7] = f2bf(hi.w * sc);
    *reinterpret_cast<u16x8*>(&wp[(size_t)slot * 8]) = o;
}

// ---------------------------------------------------------------------------
// QKV projection, single pass (unchanged from R5).
// ---------------------------------------------------------------------------
__global__ __launch_bounds__(512) void qkv_proj(
    const float* __restrict__ x, const u16* __restrict__ wp,
    u16* __restrict__ kb, u16* __restrict__ qb, u16* __restrict__ vb)
{
    __shared__ float xs[2][32 * 68];

    const int tid  = threadIdx.x;
    const int lane = tid & 63;
    const int w    = tid >> 6;        // 0..7
    const int rg   = w & 1;           // rowgroup of 16
    const int cg   = w >> 1;          // colgroup of 48 (3 tiles)
    const int l15  = lane & 15;
    const int lg   = lane >> 4;

    const int row0 = blockIdx.x * 32;
    const int sr   = tid >> 4;
    const int scc  = (tid & 15) << 2;

    f32x4 acc[3];
#pragma unroll
    for (int nt = 0; nt < 3; ++nt)
#pragma unroll
        for (int r = 0; r < 4; ++r) acc[nt][r] = 0.f;

    const float* __restrict__ xsrc = &x[(size_t)(row0 + sr) * Cn + scc];

    float4 g = *reinterpret_cast<const float4*>(xsrc);
    *reinterpret_cast<float4*>(&xs[0][sr * 68 + scc]) = g;
    __syncthreads();

    for (int ks = 0; ks < 16; ++ks) {
        const int cur = ks & 1;
        if (ks < 15)
            g = *reinterpret_cast<const float4*>(xsrc + (ks + 1) * 64);
#pragma unroll
        for (int kc2 = 0; kc2 < 2; ++kc2) {
            const float* ap = &xs[cur][(rg * 16 + l15) * 68 + kc2 * 32 + (lg << 3)];
            f32x4 a0 = *reinterpret_cast<const f32x4*>(ap);
            f32x4 a1 = *reinterpret_cast<const f32x4*>(ap + 4);
            bf16x8 a;
            a[0] = (__bf16)a0[0]; a[1] = (__bf16)a0[1];
            a[2] = (__bf16)a0[2]; a[3] = (__bf16)a0[3];
            a[4] = (__bf16)a1[0]; a[5] = (__bf16)a1[1];
            a[6] = (__bf16)a1[2]; a[7] = (__bf16)a1[3];
            const int kcg = ks * 2 + kc2;
#pragma unroll
            for (int nt = 0; nt < 3; ++nt) {
                const int n16 = cg * 3 + nt;
                bf16x8 bfr = *reinterpret_cast<const bf16x8*>(
                    &wp[(size_t)((n16 * 32 + kcg) * 64 + lane) * 8]);
                acc[nt] = __builtin_amdgcn_mfma_f32_16x16x32_bf16(a, bfr, acc[nt], 0, 0, 0);
            }
        }
        if (ks < 15)
            *reinterpret_cast<float4*>(&xs[cur ^ 1][sr * 68 + scc]) = g;
        __syncthreads();
    }

#pragma unroll
    for (int nt = 0; nt < 3; ++nt) {
        const int n16  = cg * 3 + nt;
        const int col0 = n16 * 16;
        const int mat  = col0 >> 6;
        u16* __restrict__ ob = (mat == 0) ? kb : (mat == 1) ? qb : vb;
        const int h = (col0 & 63) + l15;
#pragma unroll
        for (int reg = 0; reg < 4; ++reg) {
            const int grow = row0 + rg * 16 + (lg << 2) + reg;
            ob[(size_t)grow * Hn + h] = f2bf(acc[nt][reg]);
        }
    }
}

// ---------------------------------------------------------------------------
// Causal flash attention, split-KV with 512-key chunks (8 tiles, <=4 rounds).
// 640 blocks; 4 waves = 2 rowgroups x 2 key-parities.  Defer-max kept; no
// setprio.  Single-chunk qtiles (qt<16) write `out` directly (no partial).
// LDS 45KB -> 3 blocks/CU.
// ---------------------------------------------------------------------------
__global__ __launch_bounds__(256) void attn(
    const u16* __restrict__ qb, const u16* __restrict__ kb,
    const u16* __restrict__ vb, float* __restrict__ Opart,
    float* __restrict__ mlb, float* __restrict__ out)
{
    __shared__ u16 Ks[2][64 * 72];
    __shared__ u16 VTs[2][64 * 72];
    __shared__ u16 Pl[4][16 * 72];

    const int tid  = threadIdx.x;
    const int lane = tid & 63;
    const int w    = tid >> 6;
    const int g    = w >> 1;
    const int p    = w & 1;
    const int l15  = lane & 15;
    const int lg   = lane >> 4;

    // decode (b, qt, c): group gq = qt>>4 has 16 qtiles x (gq+1) chunks of 512
    const int bid = blockIdx.x;
    const int b = bid / 160;
    const int r = bid % 160;
    int gq = 3;
    while (8 * gq * (gq + 1) > r) --gq;
    const int rr = r - 8 * gq * (gq + 1);
    const int qt = gq * 16 + rr / (gq + 1);
    const int c  = rr % (gq + 1);
    const int c8 = c * 8;

    const int t0  = qt * 32;
    const int wr0 = t0 + g * 16;
    const int nkt = (qt >> 1) + 1;               // 64-key tiles total
    const int rounds = (nkt - c8 + 1) >> 1 < 4 ? (nkt - c8 + 1) >> 1 : 4;
    const size_t kvbase = (size_t)b * Tn * Hn;

    bf16x8 qf[2];
    {
        const u16* qrow = qb + ((size_t)(b * Tn + wr0 + l15)) * Hn;
        qf[0] = *reinterpret_cast<const bf16x8*>(&qrow[(lg << 3)]);
        qf[1] = *reinterpret_cast<const bf16x8*>(&qrow[32 + (lg << 3)]);
    }

    f32x4 o[4];
    float m[4], ls[4];
#pragma unroll
    for (int nt = 0; nt < 4; ++nt)
#pragma unroll
        for (int rg2 = 0; rg2 < 4; ++rg2) o[nt][rg2] = 0.f;
#pragma unroll
    for (int rg2 = 0; rg2 < 4; ++rg2) { m[rg2] = -INFINITY; ls[rg2] = 0.f; }

    for (int s = 0; s < rounds; ++s) {
        const int kt0 = c8 + 2 * s, kt1 = kt0 + 1;
        {
#pragma unroll
            for (int i = 0; i < 2; ++i) {
                int cc = tid + 256 * i;
                int rr2 = cc >> 3, cb = (cc & 7) << 3;
                *reinterpret_cast<u16x8*>(&Ks[0][rr2 * 72 + cb]) =
                    *reinterpret_cast<const u16x8*>(&kb[kvbase + (size_t)(kt0 * 64 + rr2) * Hn + cb]);
            }
#pragma unroll
            for (int i = 0; i < 2; ++i) {
                int cc = tid + 256 * i;
                int k = cc & 63, d0 = (cc >> 6) << 3;
                u16x8 v = *reinterpret_cast<const u16x8*>(&vb[kvbase + (size_t)(kt0 * 64 + k) * Hn + d0]);
#pragma unroll
                for (int j = 0; j < 8; ++j) VTs[0][(d0 + j) * 72 + k] = v[j];
            }
        }
        if (kt1 < nkt) {
#pragma unroll
            for (int i = 0; i < 2; ++i) {
                int cc = tid + 256 * i;
                int rr2 = cc >> 3, cb = (cc & 7) << 3;
                *reinterpret_cast<u16x8*>(&Ks[1][rr2 * 72 + cb]) =
                    *reinterpret_cast<const u16x8*>(&kb[kvbase + (size_t)(kt1 * 64 + rr2) * Hn + cb]);
            }
#pragma unroll
            for (int i = 0; i < 2; ++i) {
                int cc = tid + 256 * i;
                int k = cc & 63, d0 = (cc >> 6) << 3;
                u16x8 v = *reinterpret_cast<const u16x8*>(&vb[kvbase + (size_t)(kt1 * 64 + k) * Hn + d0]);
#pragma unroll
                for (int j = 0; j < 8; ++j) VTs[1][(d0 + j) * 72 + k] = v[j];
            }
        }
        __syncthreads();

        const int mykt = kt0 + p;
        if (mykt < nkt) {
            f32x4 sf[4];
#pragma unroll
            for (int nt = 0; nt < 4; ++nt)
#pragma unroll
                for (int rg2 = 0; rg2 < 4; ++rg2) sf[nt][rg2] = 0.f;
#pragma unroll
            for (int kc = 0; kc < 2; ++kc) {
#pragma unroll
                for (int nt = 0; nt < 4; ++nt) {
                    bf16x8 kf = *reinterpret_cast<const bf16x8*>(
                        &Ks[p][(nt * 16 + l15) * 72 + kc * 32 + (lg << 3)]);
                    sf[nt] = __builtin_amdgcn_mfma_f32_16x16x32_bf16(qf[kc], kf, sf[nt], 0, 0, 0);
                }
            }
            if (mykt * 64 + 63 > wr0) {
#pragma unroll
                for (int nt = 0; nt < 4; ++nt) {
                    int kg = mykt * 64 + nt * 16 + l15;
#pragma unroll
                    for (int reg = 0; reg < 4; ++reg) {
                        int tq = wr0 + (lg << 2) + reg;
                        if (kg > tq) sf[nt][reg] = -INFINITY;
                    }
                }
            }
            // tile max + defer-max (THR=8)
            float tm[4];
            bool defok = true;
#pragma unroll
            for (int reg = 0; reg < 4; ++reg) {
                float t = fmaxf(fmaxf(sf[0][reg], sf[1][reg]),
                                fmaxf(sf[2][reg], sf[3][reg]));
#pragma unroll
                for (int off = 1; off < 16; off <<= 1)
                    t = fmaxf(t, __shfl_xor(t, off, 64));
                tm[reg] = t;
                defok = defok && (t <= m[reg] + 8.f);
            }
            if (!__all(defok ? 1 : 0)) {
#pragma unroll
                for (int reg = 0; reg < 4; ++reg) {
                    float nm = fmaxf(m[reg], tm[reg]);
                    float al = __expf(m[reg] - nm);   // first tile: m=-inf -> al=0
                    ls[reg] *= al;
#pragma unroll
                    for (int nt = 0; nt < 4; ++nt) o[nt][reg] *= al;
                    m[reg] = nm;
                }
            }
            float pv[4][4];
#pragma unroll
            for (int reg = 0; reg < 4; ++reg) {
                float rs = 0.f;
#pragma unroll
                for (int nt = 0; nt < 4; ++nt) {
                    pv[nt][reg] = __expf(sf[nt][reg] - m[reg]);
                    rs += pv[nt][reg];
                }
#pragma unroll
                for (int off = 1; off < 16; off <<= 1)
                    rs += __shfl_xor(rs, off, 64);
                ls[reg] += rs;
            }
#pragma unroll
            for (int nt = 0; nt < 4; ++nt)
#pragma unroll
                for (int reg = 0; reg < 4; ++reg)
                    Pl[w][((lg << 2) + reg) * 72 + nt * 16 + l15] = f2bf(pv[nt][reg]);
#pragma unroll
            for (int kc = 0; kc < 2; ++kc) {
                bf16x8 pa = *reinterpret_cast<const bf16x8*>(
                    &Pl[w][l15 * 72 + kc * 32 + (lg << 3)]);
#pragma unroll
                for (int nt = 0; nt < 4; ++nt) {
                    bf16x8 vf = *reinterpret_cast<const bf16x8*>(
                        &VTs[p][(nt * 16 + l15) * 72 + kc * 32 + (lg << 3)]);
                    o[nt] = __builtin_amdgcn_mfma_f32_16x16x32_bf16(pa, vf, o[nt], 0, 0, 0);
                }
            }
        }
        __syncthreads();
    }

    // in-block parity merge
    float* slab = reinterpret_cast<float*>(&Ks[0][0]);
    float* sb = slab + g * (24 * 64);
    if (p == 1) {
#pragma unroll
        for (int nt = 0; nt < 4; ++nt)
#pragma unroll
            for (int reg = 0; reg < 4; ++reg)
                sb[(nt * 4 + reg) * 64 + lane] = o[nt][reg];
#pragma unroll
        for (int reg = 0; reg < 4; ++reg) {
            sb[(16 + reg) * 64 + lane] = m[reg];
            sb[(20 + reg) * 64 + lane] = ls[reg];
        }
    }
    __syncthreads();
    if (p == 0) {
        if (gq == 0) {
            // single-chunk qtile: finalize directly to out
#pragma unroll
            for (int reg = 0; reg < 4; ++reg) {
                float mB = sb[(16 + reg) * 64 + lane];
                float lB = sb[(20 + reg) * 64 + lane];
                float ms = fmaxf(m[reg], mB);
                float aA = __expf(m[reg] - ms);
                float aB = __expf(mB - ms);
                float inv = 1.0f / (aA * ls[reg] + aB * lB);
                int grow = t0 + g * 16 + (lg << 2) + reg;
                float* orow = out + ((size_t)(b * Tn) + grow) * Hn;
#pragma unroll
                for (int nt = 0; nt < 4; ++nt)
                    orow[nt * 16 + l15] =
                        (aA * o[nt][reg] + aB * sb[(nt * 4 + reg) * 64 + lane]) * inv;
            }
        } else {
            const size_t pidx = (size_t)(b * 64 + qt) * 4 + c;
            float* __restrict__ ob = Opart + pidx * 2048;
#pragma unroll
            for (int reg = 0; reg < 4; ++reg) {
                float mB = sb[(16 + reg) * 64 + lane];
                float lB = sb[(20 + reg) * 64 + lane];
                float ms = fmaxf(m[reg], mB);
                float aA = __expf(m[reg] - ms);
                float aB = __expf(mB - ms);
                int row32 = g * 16 + (lg << 2) + reg;
                if (l15 == 0) {
                    float* mlp = mlb + pidx * 64 + row32 * 2;
                    mlp[0] = ms;
                    mlp[1] = aA * ls[reg] + aB * lB;
                }
#pragma unroll
                for (int nt = 0; nt < 4; ++nt)
                    ob[row32 * 64 + nt * 16 + l15] =
                        aA * o[nt][reg] + aB * sb[(nt * 4 + reg) * 64 + lane];
            }
        }
    }
}

// ---------------------------------------------------------------------------
// Combine KV-chunk partials (qt >= 16 only; <=4 chunks).  grid 192.
// ---------------------------------------------------------------------------
__global__ __launch_bounds__(256) void attn_merge(
    const float* __restrict__ Opart, const float* __restrict__ mlb,
    float* __restrict__ out)
{
    const int bid = blockIdx.x;
    const int b  = bid / 48;
    const int qt = 16 + bid % 48;
    const int nch = (qt >> 4) + 1;               // 2..4
    const int t = threadIdx.x;
    const int row = t >> 3, d0 = (t & 7) << 3;
    const size_t pbase = (size_t)(b * 64 + qt) * 4;

    float mc[4], lc[4];
#pragma unroll
    for (int cc = 0; cc < 4; ++cc) {
        if (cc < nch) {
            const float* mlp = mlb + (pbase + cc) * 64 + row * 2;
            mc[cc] = mlp[0];
            lc[cc] = mlp[1];
        } else { mc[cc] = -INFINITY; lc[cc] = 0.f; }
    }
    float mfin = fmaxf(fmaxf(mc[0], mc[1]), fmaxf(mc[2], mc[3]));

    float wgt[4], l = 0.f;
#pragma unroll
    for (int cc = 0; cc < 4; ++cc) {
        wgt[cc] = (cc < nch) ? __expf(mc[cc] - mfin) : 0.f;
        l += lc[cc] * wgt[cc];
    }

    f32x4 O0 = {0.f, 0.f, 0.f, 0.f}, O1 = {0.f, 0.f, 0.f, 0.f};
#pragma unroll
    for (int cc = 0; cc < 4; ++cc) {
        if (cc < nch) {
            const float* op = Opart + (pbase + cc) * 2048 + row * 64 + d0;
            f32x4 c0 = *reinterpret_cast<const f32x4*>(op);
            f32x4 c1 = *reinterpret_cast<const f32x4*>(op + 4);
            O0 += c0 * wgt[cc];
            O1 += c1 * wgt[cc];
        }
    }
    float inv = 1.f / l;
    float* orow = out + ((size_t)(b * Tn + qt * 32 + row)) * Hn + d0;
    *reinterpret_cast<f32x4*>(orow)     = O0 * inv;
    *reinterpret_cast<f32x4*>(orow + 4) = O1 * inv;
}

extern "C" void kernel_launch(void* const* d_in, const int* in_sizes, int n_in,
                              void* d_out, int out_size, void* d_ws, size_t ws_size,
                              hipStream_t stream) {
    const float* x  = (const float*)d_in[0];
    const float* Wk = (const float*)d_in[1];
    const float* Wq = (const float*)d_in[2];
    const float* Wv = (const float*)d_in[3];
    float* out = (float*)d_out;

    const size_t rows = (size_t)4 * Tn;            // 8192
    u16* kbuf = (u16*)d_ws;                        // [8192][64] bf16
    u16* qbuf = kbuf + rows * Hn;
    u16* vbuf = qbuf + rows * Hn;
    u16* wpk  = vbuf + rows * Hn;                  // 196608 u16
    float* Opart = (float*)(wpk + 196608);         // [256][4][32][64] f32
    float* mlb   = Opart + (size_t)256 * 4 * 2048; // [256][4][32][2] f32

    wpack_kernel<<<96, 256, 0, stream>>>(Wk, Wq, Wv, wpk);
    qkv_proj<<<256, 512, 0, stream>>>(x, wpk, kbuf, qbuf, vbuf);
    attn<<<640, 256, 0, stream>>>(qbuf, kbuf, vbuf, Opart, mlb, out);
    attn_merge<<<192, 256, 0, stream>>>(Opart, mlb, out);
}